// Round 6
// baseline (243.583 us; speedup 1.0000x reference)
//
#include <hip/hip_runtime.h>
#include <hip/hip_fp16.h>

#define T_STEPS 32
#define BATCH   65536
#define IN_DIM  27
#define INP     28          // W_ih rows padded to 28 floats (16B-aligned)
#define H_DIM   10
#define G_DIM   40          // 4*H
#define H2_DIM  5
#define GP      20          // packed gate-row pairs per (t, elem)

__device__ __forceinline__ float fast_exp2(float v) { return __builtin_amdgcn_exp2f(v); }
__device__ __forceinline__ float fast_rcp(float v)  { return __builtin_amdgcn_rcpf(v); }
__device__ __forceinline__ float fast_sigmoid(float v) {
    return fast_rcp(1.f + fast_exp2(v * -1.4426950408889634f));
}
__device__ __forceinline__ float fast_tanh(float v) {
    return 1.f - 2.f * fast_rcp(1.f + fast_exp2(v * 2.8853900817779268f));
}

// ---------------------------------------------------------------------------
// Pass 1 (E=2, fp16 out): each thread computes the 40 x-gates for TWO batch
// elements so every ds_read_b128 weight broadcast feeds 8 FMAs (was 4 -> LDS
// cost/elem halves). Output packed as half2 pairs (rows 2jp, 2jp+1):
// gx[t][jp][b], jp in [0,20) -> write traffic 335 MB -> 168 MB.
// ---------------------------------------------------------------------------
__global__ __launch_bounds__(256, 4) void input_proj_h2_kernel(
    const float* __restrict__ word,   // [T, B, IN]
    const float* __restrict__ W_ih,   // [4H, IN]
    const float* __restrict__ b_ih,   // [4H]
    const float* __restrict__ b_hh,   // [4H]
    __half2* __restrict__ gx)         // [T, 20, B] packed pairs
{
    __shared__ float s_x[256 * IN_DIM];   // 27648 B (reused for both chunks)
    __shared__ float s_w[G_DIM * INP];    //  4480 B
    __shared__ float s_b[G_DIM];

    const int tid = threadIdx.x;
    const int t   = blockIdx.y;
    const int b0  = blockIdx.x * 512;     // this block covers 512 elements

    // stage weights/bias once
    for (int idx = tid; idx < G_DIM * INP; idx += 256) {
        const int j = idx / INP, k = idx - j * INP;
        s_w[idx] = (k < IN_DIM) ? W_ih[j * IN_DIM + k] : 0.f;
    }
    if (tid < G_DIM) s_b[tid] = b_ih[tid] + b_hh[tid];

    // chunk A: elems [b0, b0+256) -> x1
    const float* srcA = word + ((size_t)t * BATCH + b0) * IN_DIM;
#pragma unroll
    for (int i = 0; i < IN_DIM; ++i) s_x[tid + 256 * i] = srcA[tid + 256 * i];
    __syncthreads();
    float x1[INP];
#pragma unroll
    for (int k = 0; k < IN_DIM; ++k) x1[k] = s_x[tid * IN_DIM + k];   // stride 27: conflict-free
    x1[IN_DIM] = 0.f;
    __syncthreads();   // everyone done reading before overwrite

    // chunk B: elems [b0+256, b0+512) -> x2
    const float* srcB = srcA + 256 * IN_DIM;
#pragma unroll
    for (int i = 0; i < IN_DIM; ++i) s_x[tid + 256 * i] = srcB[tid + 256 * i];
    __syncthreads();
    float x2[INP];
#pragma unroll
    for (int k = 0; k < IN_DIM; ++k) x2[k] = s_x[tid * IN_DIM + k];
    x2[IN_DIM] = 0.f;

    __half2* dst1 = gx + (size_t)t * GP * BATCH + (size_t)(b0 + tid);
    __half2* dst2 = dst1 + 256;
#pragma unroll
    for (int jp = 0; jp < GP; ++jp) {
        const float2 bb = *(const float2*)(s_b + 2 * jp);
        float a0 = bb.x, a1 = bb.y;    // elem 1, rows 2jp / 2jp+1
        float c0 = bb.x, c1 = bb.y;    // elem 2
        const float* w0 = s_w + (2 * jp) * INP;
        const float* w1 = w0 + INP;
#pragma unroll
        for (int k = 0; k < INP; k += 4) {
            const float4 q0 = *(const float4*)(w0 + k);   // one b128 feeds 8 FMAs
            const float4 q1 = *(const float4*)(w1 + k);
            a0 = fmaf(q0.x, x1[k], fmaf(q0.y, x1[k+1], fmaf(q0.z, x1[k+2], fmaf(q0.w, x1[k+3], a0))));
            a1 = fmaf(q1.x, x1[k], fmaf(q1.y, x1[k+1], fmaf(q1.z, x1[k+2], fmaf(q1.w, x1[k+3], a1))));
            c0 = fmaf(q0.x, x2[k], fmaf(q0.y, x2[k+1], fmaf(q0.z, x2[k+2], fmaf(q0.w, x2[k+3], c0))));
            c1 = fmaf(q1.x, x2[k], fmaf(q1.y, x2[k+1], fmaf(q1.z, x2[k+2], fmaf(q1.w, x2[k+3], c1))));
        }
        dst1[(size_t)jp * BATCH] = __floats2half2_rn(a0, a1);   // coalesced (lanes = e)
        dst2[(size_t)jp * BATCH] = __floats2half2_rn(c0, c1);
    }
}

// ---------------------------------------------------------------------------
// Pass 2: 4 threads/elem, W_hh slice (100 floats) in VGPRs, zero in-loop LDS.
// fp16 gx: 5 dword (half2) loads/step, prefetch depth 2 (raw half2 kept
// packed until consume so no premature vmcnt wait). Quad all-gather of
// activated gates via shfl_xor + role decode, valid in all lanes (R5-proven).
// ---------------------------------------------------------------------------
__global__
__attribute__((amdgpu_flat_work_group_size(256, 256), amdgpu_waves_per_eu(2, 2)))
void recurrence4h_kernel(
    const __half2* __restrict__ gx,   // [T, 20, B]
    const float* __restrict__ W_hh,   // [4H, H]
    const float* __restrict__ W_fc,   // [H2, H]
    const float* __restrict__ b_fc,   // [H2]
    const float* __restrict__ W_out,  // [1, H2]
    const float* __restrict__ b_out,  // [1]
    float* __restrict__ out)          // [B]
{
    const int tid = threadIdx.x;
    const int r   = tid & 3;                       // gate type: 0=i 1=f 2=g 3=o
    const int e   = blockIdx.x * 64 + (tid >> 2);  // batch element

    // my 10 W_hh rows -> registers
    float wh[10][10];
    {
        const float* wsrc = W_hh + (size_t)(r * 10) * H_DIM;
#pragma unroll
        for (int j = 0; j < 10; ++j)
#pragma unroll
            for (int n = 0; n < 10; ++n) wh[j][n] = wsrc[j * H_DIM + n];
    }

    const bool  is_tanh = (r == 2);
    const float kexp    = is_tanh ? 2.8853900817779268f : -1.4426950408889634f;
    const bool  m1 = (r & 1) != 0;
    const bool  m2 = (r & 2) != 0;

    float h[H_DIM], c[H_DIM];
#pragma unroll
    for (int m = 0; m < H_DIM; ++m) { h[m] = 0.f; c[m] = 0.f; }

    // my 5 packed rows (jp = r*5+p), column e
    const __half2* gbase = gx + (size_t)(r * 5) * BATCH + e;
    const size_t tstride = (size_t)GP * BATCH;

    // prefetch pipeline: raw0 = t, raw1 = t+1 (kept packed)
    __half2 raw0[5], raw1[5];
#pragma unroll
    for (int p = 0; p < 5; ++p) raw0[p] = gbase[(size_t)p * BATCH];
#pragma unroll
    for (int p = 0; p < 5; ++p) raw1[p] = gbase[tstride + (size_t)p * BATCH];

    for (int t = 0; t < T_STEPS; ++t) {
        // issue t+2 loads first (depth-2: ~1400 cyc of compute covers them)
        __half2 raw2[5];
        {
            const int tn = (t + 2 < T_STEPS) ? (t + 2) : (T_STEPS - 1);
            const __half2* gp = gbase + (size_t)tn * tstride;
#pragma unroll
            for (int p = 0; p < 5; ++p) raw2[p] = gp[(size_t)p * BATCH];
        }

        // unpack current step (loaded 2 iterations ago -> no wait)
        float cur[10];
#pragma unroll
        for (int p = 0; p < 5; ++p) {
            cur[2 * p]     = __low2float(raw0[p]);
            cur[2 * p + 1] = __high2float(raw0[p]);
        }

        // h-part (VGPR weights) + my activation per owned row
        float act[10];
#pragma unroll
        for (int j = 0; j < 10; ++j) {
            float a = cur[j];
#pragma unroll
            for (int n = 0; n < H_DIM; ++n) a = fmaf(wh[j][n], h[n], a);
            const float e2 = fast_exp2(a * kexp);
            const float u  = fast_rcp(1.f + e2);
            act[j] = is_tanh ? fmaf(-2.f, u, 1.f) : u;
        }

        // quad all-gather + role decode + update (valid in ALL lanes)
#pragma unroll
        for (int m = 0; m < H_DIM; ++m) {
            const float s  = act[m];
            const float x1 = __shfl_xor(s, 1);
            const float x2 = __shfl_xor(s, 2);
            const float x3 = __shfl_xor(s, 3);
            const float tA  = m1 ? x1 : s;
            const float tB  = m1 ? x3 : x2;
            const float tAp = m1 ? s  : x1;
            const float tBp = m1 ? x2 : x3;
            const float iv = m2 ? tB  : tA;
            const float fv = m2 ? tBp : tAp;
            const float gv = m2 ? tA  : tB;
            const float ov = m2 ? tAp : tBp;
            const float cn = fmaf(fv, c[m], iv * gv);
            const float hv = ov * fast_tanh(cn);
            h[m] = fmaxf(hv, 0.f);   // reference ReLUs both carries
            c[m] = fmaxf(cn, 0.f);
        }

        // rotate pipeline
#pragma unroll
        for (int p = 0; p < 5; ++p) { raw0[p] = raw1[p]; raw1[p] = raw2[p]; }
    }

    // head: one lane per quad
    if (r == 0) {
        float acc = b_out[0];
#pragma unroll
        for (int p = 0; p < H2_DIM; ++p) {
            float y = b_fc[p];
            const float* wf = W_fc + p * H_DIM;
#pragma unroll
            for (int m = 0; m < H_DIM; ++m) y = fmaf(wf[m], h[m], y);
            y = fmaxf(y, 0.f);
            acc = fmaf(W_out[p], y, acc);
        }
        out[e] = fast_sigmoid(acc);
    }
}

// ---------------------------------------------------------------------------
// Fallback (fused, known-correct) if workspace is too small.
// ---------------------------------------------------------------------------
__global__ __launch_bounds__(256, 1) void lstm_word_fused_kernel(
    const float* __restrict__ word, const float* __restrict__ W_ih,
    const float* __restrict__ W_hh, const float* __restrict__ b_ih,
    const float* __restrict__ b_hh, const float* __restrict__ W_fc,
    const float* __restrict__ b_fc, const float* __restrict__ W_out,
    const float* __restrict__ b_out, float* __restrict__ out)
{
    const int b = blockIdx.x * blockDim.x + threadIdx.x;
    float bias[G_DIM];
#pragma unroll
    for (int j = 0; j < G_DIM; ++j) bias[j] = b_ih[j] + b_hh[j];
    float h[H_DIM], c[H_DIM];
#pragma unroll
    for (int m = 0; m < H_DIM; ++m) { h[m] = 0.f; c[m] = 0.f; }
    const size_t t_stride = (size_t)BATCH * IN_DIM;
    const size_t row_off  = (size_t)b * IN_DIM;
    float x[IN_DIM];
    {
        const float* xp = word + row_off;
#pragma unroll
        for (int k = 0; k < IN_DIM; ++k) x[k] = xp[k];
    }
    for (int t = 0; t < T_STEPS; ++t) {
        float xn[IN_DIM];
        {
            const int tn = (t + 1 < T_STEPS) ? (t + 1) : t;
            const float* xq = word + (size_t)tn * t_stride + row_off;
#pragma unroll
            for (int k = 0; k < IN_DIM; ++k) xn[k] = xq[k];
        }
        float hn[H_DIM];
#pragma unroll
        for (int m = 0; m < H_DIM; ++m) {
            float ai = bias[m], af = bias[m + H_DIM], ag = bias[m + 2*H_DIM], ao = bias[m + 3*H_DIM];
            const float* wi = W_ih + m * IN_DIM;
            const float* wf = W_ih + (m + H_DIM) * IN_DIM;
            const float* wg = W_ih + (m + 2*H_DIM) * IN_DIM;
            const float* wo = W_ih + (m + 3*H_DIM) * IN_DIM;
#pragma unroll
            for (int k = 0; k < IN_DIM; ++k) {
                const float xv = x[k];
                ai = fmaf(wi[k], xv, ai); af = fmaf(wf[k], xv, af);
                ag = fmaf(wg[k], xv, ag); ao = fmaf(wo[k], xv, ao);
            }
            const float* hi = W_hh + m * H_DIM;
            const float* hf = W_hh + (m + H_DIM) * H_DIM;
            const float* hg = W_hh + (m + 2*H_DIM) * H_DIM;
            const float* ho = W_hh + (m + 3*H_DIM) * H_DIM;
#pragma unroll
            for (int n = 0; n < H_DIM; ++n) {
                const float hv = h[n];
                ai = fmaf(hi[n], hv, ai); af = fmaf(hf[n], hv, af);
                ag = fmaf(hg[n], hv, ag); ao = fmaf(ho[n], hv, ao);
            }
            const float iv = fast_sigmoid(ai), fv = fast_sigmoid(af);
            const float gv = fast_tanh(ag),    ov = fast_sigmoid(ao);
            const float cn = fmaf(fv, c[m], iv * gv);
            const float hv = ov * fast_tanh(cn);
            hn[m] = fmaxf(hv, 0.f);
            c[m]  = fmaxf(cn, 0.f);
        }
#pragma unroll
        for (int m = 0; m < H_DIM; ++m) h[m] = hn[m];
#pragma unroll
        for (int k = 0; k < IN_DIM; ++k) x[k] = xn[k];
    }
    float acc = b_out[0];
#pragma unroll
    for (int p = 0; p < H2_DIM; ++p) {
        float y = b_fc[p];
        const float* wf = W_fc + p * H_DIM;
#pragma unroll
        for (int m = 0; m < H_DIM; ++m) y = fmaf(wf[m], h[m], y);
        y = fmaxf(y, 0.f);
        acc = fmaf(W_out[p], y, acc);
    }
    out[b] = fast_sigmoid(acc);
}

extern "C" void kernel_launch(void* const* d_in, const int* in_sizes, int n_in,
                              void* d_out, int out_size, void* d_ws, size_t ws_size,
                              hipStream_t stream) {
    const float* word  = (const float*)d_in[0];
    const float* W_ih  = (const float*)d_in[1];
    const float* W_hh  = (const float*)d_in[2];
    const float* b_ih  = (const float*)d_in[3];
    const float* b_hh  = (const float*)d_in[4];
    const float* W_fc  = (const float*)d_in[5];
    const float* b_fc  = (const float*)d_in[6];
    const float* W_out = (const float*)d_in[7];
    const float* b_out = (const float*)d_in[8];
    float* out = (float*)d_out;

    const size_t need = (size_t)T_STEPS * GP * BATCH * sizeof(__half2); // 167.8 MB
    if (ws_size >= need) {
        __half2* gxbuf = (__half2*)d_ws;
        dim3 grid1(BATCH / 512, T_STEPS);
        input_proj_h2_kernel<<<grid1, 256, 0, stream>>>(word, W_ih, b_ih, b_hh, gxbuf);
        recurrence4h_kernel<<<BATCH / 64, 256, 0, stream>>>(
            gxbuf, W_hh, W_fc, b_fc, W_out, b_out, out);
    } else {
        lstm_word_fused_kernel<<<BATCH / 256, 256, 0, stream>>>(
            word, W_ih, W_hh, b_ih, b_hh, W_fc, b_fc, W_out, b_out, out);
    }
}

// Round 7
// 199.113 us; speedup vs baseline: 1.2233x; 1.2233x over previous
//
#include <hip/hip_runtime.h>
#include <hip/hip_fp16.h>

#define T_STEPS 32
#define BATCH   65536
#define IN_DIM  27
#define H_DIM   10
#define G_DIM   40          // 4*H
#define H2_DIM  5
#define GP      20          // packed gate-row pairs per (t, elem)

__device__ __forceinline__ float fast_exp2(float v) { return __builtin_amdgcn_exp2f(v); }
__device__ __forceinline__ float fast_rcp(float v)  { return __builtin_amdgcn_rcpf(v); }
__device__ __forceinline__ float fast_sigmoid(float v) {
    return fast_rcp(1.f + fast_exp2(v * -1.4426950408889634f));
}
__device__ __forceinline__ float fast_tanh(float v) {
    return 1.f - 2.f * fast_rcp(1.f + fast_exp2(v * 2.8853900817779268f));
}

// ---------------------------------------------------------------------------
// Pass 1 v3: weights via wave-uniform global reads -> s_load into SGPRs
// (scalar pipe, zero LDS traffic). LDS only stages x (coalesced HBM fetch).
// R6 lesson: weights-in-LDS made the kernel LDS-pipe-bound (~280 uniform
// ds_read_b128/wave), and the compiler remat'd x from LDS inside the loop
// (VGPR_Count=48 < live set). The asm "+v" pins x in VGPRs.
// ---------------------------------------------------------------------------
__global__ __launch_bounds__(256, 4) void input_proj_s_kernel(
    const float* __restrict__ word,   // [T, B, IN]
    const float* __restrict__ W_ih,   // [4H, IN] (contiguous 1080 floats)
    const float* __restrict__ b_ih,   // [4H]
    const float* __restrict__ b_hh,   // [4H]
    __half2* __restrict__ gx)         // [T, 20, B] packed row pairs
{
    __shared__ float s_x[256 * IN_DIM];   // 27648 B -> 5 blocks/CU

    const int tid = threadIdx.x;
    const int t   = blockIdx.y;
    const int b0  = blockIdx.x * 256;

    // coalesced stage: 256 rows x 27 floats
    const float* src = word + ((size_t)t * BATCH + b0) * IN_DIM;
#pragma unroll
    for (int i = 0; i < IN_DIM; ++i) s_x[tid + 256 * i] = src[tid + 256 * i];
    __syncthreads();

    // per-lane x -> registers (stride 27 coprime 32: conflict-free)
    float x[IN_DIM];
#pragma unroll
    for (int k = 0; k < IN_DIM; ++k) x[k] = s_x[tid * IN_DIM + k];
    // pin x in VGPRs: forbid the compiler from sinking these LDS reads
    // into the jp loop (R6's regression mechanism)
#pragma unroll
    for (int k = 0; k < IN_DIM; ++k) asm volatile("" : "+v"(x[k]));

    __half2* dst = gx + (size_t)t * GP * BATCH + (size_t)(b0 + tid);
#pragma unroll
    for (int jp = 0; jp < GP; ++jp) {
        const int r0 = 2 * jp, r1 = 2 * jp + 1;
        // all weight/bias indices are wave-uniform -> SMEM s_load stream,
        // issued on the scalar pipe in parallel with the FMAs
        float a0 = b_ih[r0] + b_hh[r0];
        float a1 = b_ih[r1] + b_hh[r1];
        const float* w0 = W_ih + r0 * IN_DIM;
        const float* w1 = W_ih + r1 * IN_DIM;
#pragma unroll
        for (int k = 0; k < IN_DIM; ++k) {
            a0 = fmaf(w0[k], x[k], a0);   // v_fma_f32 vD, sW, vX, vA (1 SGPR/inst ok)
            a1 = fmaf(w1[k], x[k], a1);
        }
        dst[(size_t)jp * BATCH] = __floats2half2_rn(a0, a1);   // coalesced 4B/lane
    }
}

// ---------------------------------------------------------------------------
// Pass 2 (R5/R6-proven): 4 threads/elem, W_hh slice in VGPRs, fp16 gx,
// prefetch depth 2, quad all-gather via shfl_xor. Tweak: relu folded into
// tanh argument (relu(o*tanh(cn)) == o*tanh(relu(cn)) since o>0, tanh(0)=0).
// ---------------------------------------------------------------------------
__global__
__attribute__((amdgpu_flat_work_group_size(256, 256), amdgpu_waves_per_eu(2, 2)))
void recurrence4h_kernel(
    const __half2* __restrict__ gx,   // [T, 20, B]
    const float* __restrict__ W_hh,   // [4H, H]
    const float* __restrict__ W_fc,   // [H2, H]
    const float* __restrict__ b_fc,   // [H2]
    const float* __restrict__ W_out,  // [1, H2]
    const float* __restrict__ b_out,  // [1]
    float* __restrict__ out)          // [B]
{
    const int tid = threadIdx.x;
    const int r   = tid & 3;                       // gate type: 0=i 1=f 2=g 3=o
    const int e   = blockIdx.x * 64 + (tid >> 2);  // batch element

    // my 10 W_hh rows -> registers
    float wh[10][10];
    {
        const float* wsrc = W_hh + (size_t)(r * 10) * H_DIM;
#pragma unroll
        for (int j = 0; j < 10; ++j)
#pragma unroll
            for (int n = 0; n < 10; ++n) wh[j][n] = wsrc[j * H_DIM + n];
    }

    const bool  is_tanh = (r == 2);
    const float kexp    = is_tanh ? 2.8853900817779268f : -1.4426950408889634f;
    const bool  m1 = (r & 1) != 0;
    const bool  m2 = (r & 2) != 0;

    float h[H_DIM], c[H_DIM];
#pragma unroll
    for (int m = 0; m < H_DIM; ++m) { h[m] = 0.f; c[m] = 0.f; }

    const __half2* gbase = gx + (size_t)(r * 5) * BATCH + e;
    const size_t tstride = (size_t)GP * BATCH;

    // prefetch pipeline: raw0 = t, raw1 = t+1 (kept packed until consume)
    __half2 raw0[5], raw1[5];
#pragma unroll
    for (int p = 0; p < 5; ++p) raw0[p] = gbase[(size_t)p * BATCH];
#pragma unroll
    for (int p = 0; p < 5; ++p) raw1[p] = gbase[tstride + (size_t)p * BATCH];

    for (int t = 0; t < T_STEPS; ++t) {
        // issue t+2 loads first
        __half2 raw2[5];
        {
            const int tn = (t + 2 < T_STEPS) ? (t + 2) : (T_STEPS - 1);
            const __half2* gp = gbase + (size_t)tn * tstride;
#pragma unroll
            for (int p = 0; p < 5; ++p) raw2[p] = gp[(size_t)p * BATCH];
        }

        // unpack current step (loaded 2 iterations ago -> no wait)
        float cur[10];
#pragma unroll
        for (int p = 0; p < 5; ++p) {
            cur[2 * p]     = __low2float(raw0[p]);
            cur[2 * p + 1] = __high2float(raw0[p]);
        }

        // h-part (VGPR weights) + my activation per owned row
        float act[10];
#pragma unroll
        for (int j = 0; j < 10; ++j) {
            float a = cur[j];
#pragma unroll
            for (int n = 0; n < H_DIM; ++n) a = fmaf(wh[j][n], h[n], a);
            const float e2 = fast_exp2(a * kexp);
            const float u  = fast_rcp(1.f + e2);
            act[j] = is_tanh ? fmaf(-2.f, u, 1.f) : u;
        }

        // quad all-gather + role decode + update (valid in ALL lanes)
#pragma unroll
        for (int m = 0; m < H_DIM; ++m) {
            const float s  = act[m];
            const float x1 = __shfl_xor(s, 1);
            const float x2 = __shfl_xor(s, 2);
            const float x3 = __shfl_xor(s, 3);
            const float tA  = m1 ? x1 : s;
            const float tB  = m1 ? x3 : x2;
            const float tAp = m1 ? s  : x1;
            const float tBp = m1 ? x2 : x3;
            const float iv = m2 ? tB  : tA;
            const float fv = m2 ? tBp : tAp;
            const float gv = m2 ? tA  : tB;
            const float ov = m2 ? tAp : tBp;
            const float cn = fmaf(fv, c[m], iv * gv);
            c[m] = fmaxf(cn, 0.f);               // relu(c) first...
            h[m] = ov * fast_tanh(c[m]);         // == relu(o*tanh(cn)), o>0
        }

        // rotate pipeline
#pragma unroll
        for (int p = 0; p < 5; ++p) { raw0[p] = raw1[p]; raw1[p] = raw2[p]; }
    }

    // head: one lane per quad
    if (r == 0) {
        float acc = b_out[0];
#pragma unroll
        for (int p = 0; p < H2_DIM; ++p) {
            float y = b_fc[p];
            const float* wf = W_fc + p * H_DIM;
#pragma unroll
            for (int m = 0; m < H_DIM; ++m) y = fmaf(wf[m], h[m], y);
            y = fmaxf(y, 0.f);
            acc = fmaf(W_out[p], y, acc);
        }
        out[e] = fast_sigmoid(acc);
    }
}

// ---------------------------------------------------------------------------
// Fallback (fused, known-correct) if workspace is too small.
// ---------------------------------------------------------------------------
__global__ __launch_bounds__(256, 1) void lstm_word_fused_kernel(
    const float* __restrict__ word, const float* __restrict__ W_ih,
    const float* __restrict__ W_hh, const float* __restrict__ b_ih,
    const float* __restrict__ b_hh, const float* __restrict__ W_fc,
    const float* __restrict__ b_fc, const float* __restrict__ W_out,
    const float* __restrict__ b_out, float* __restrict__ out)
{
    const int b = blockIdx.x * blockDim.x + threadIdx.x;
    float bias[G_DIM];
#pragma unroll
    for (int j = 0; j < G_DIM; ++j) bias[j] = b_ih[j] + b_hh[j];
    float h[H_DIM], c[H_DIM];
#pragma unroll
    for (int m = 0; m < H_DIM; ++m) { h[m] = 0.f; c[m] = 0.f; }
    const size_t t_stride = (size_t)BATCH * IN_DIM;
    const size_t row_off  = (size_t)b * IN_DIM;
    float x[IN_DIM];
    {
        const float* xp = word + row_off;
#pragma unroll
        for (int k = 0; k < IN_DIM; ++k) x[k] = xp[k];
    }
    for (int t = 0; t < T_STEPS; ++t) {
        float xn[IN_DIM];
        {
            const int tn = (t + 1 < T_STEPS) ? (t + 1) : t;
            const float* xq = word + (size_t)tn * t_stride + row_off;
#pragma unroll
            for (int k = 0; k < IN_DIM; ++k) xn[k] = xq[k];
        }
        float hn[H_DIM];
#pragma unroll
        for (int m = 0; m < H_DIM; ++m) {
            float ai = bias[m], af = bias[m + H_DIM], ag = bias[m + 2*H_DIM], ao = bias[m + 3*H_DIM];
            const float* wi = W_ih + m * IN_DIM;
            const float* wf = W_ih + (m + H_DIM) * IN_DIM;
            const float* wg = W_ih + (m + 2*H_DIM) * IN_DIM;
            const float* wo = W_ih + (m + 3*H_DIM) * IN_DIM;
#pragma unroll
            for (int k = 0; k < IN_DIM; ++k) {
                const float xv = x[k];
                ai = fmaf(wi[k], xv, ai); af = fmaf(wf[k], xv, af);
                ag = fmaf(wg[k], xv, ag); ao = fmaf(wo[k], xv, ao);
            }
            const float* hi = W_hh + m * H_DIM;
            const float* hf = W_hh + (m + H_DIM) * H_DIM;
            const float* hg = W_hh + (m + 2*H_DIM) * H_DIM;
            const float* ho = W_hh + (m + 3*H_DIM) * H_DIM;
#pragma unroll
            for (int n = 0; n < H_DIM; ++n) {
                const float hv = h[n];
                ai = fmaf(hi[n], hv, ai); af = fmaf(hf[n], hv, af);
                ag = fmaf(hg[n], hv, ag); ao = fmaf(ho[n], hv, ao);
            }
            const float iv = fast_sigmoid(ai), fv = fast_sigmoid(af);
            const float gv = fast_tanh(ag),    ov = fast_sigmoid(ao);
            const float cn = fmaf(fv, c[m], iv * gv);
            const float hv = ov * fast_tanh(cn);
            hn[m] = fmaxf(hv, 0.f);
            c[m]  = fmaxf(cn, 0.f);
        }
#pragma unroll
        for (int m = 0; m < H_DIM; ++m) h[m] = hn[m];
#pragma unroll
        for (int k = 0; k < IN_DIM; ++k) x[k] = xn[k];
    }
    float acc = b_out[0];
#pragma unroll
    for (int p = 0; p < H2_DIM; ++p) {
        float y = b_fc[p];
        const float* wf = W_fc + p * H_DIM;
#pragma unroll
        for (int m = 0; m < H_DIM; ++m) y = fmaf(wf[m], h[m], y);
        y = fmaxf(y, 0.f);
        acc = fmaf(W_out[p], y, acc);
    }
    out[b] = fast_sigmoid(acc);
}

extern "C" void kernel_launch(void* const* d_in, const int* in_sizes, int n_in,
                              void* d_out, int out_size, void* d_ws, size_t ws_size,
                              hipStream_t stream) {
    const float* word  = (const float*)d_in[0];
    const float* W_ih  = (const float*)d_in[1];
    const float* W_hh  = (const float*)d_in[2];
    const float* b_ih  = (const float*)d_in[3];
    const float* b_hh  = (const float*)d_in[4];
    const float* W_fc  = (const float*)d_in[5];
    const float* b_fc  = (const float*)d_in[6];
    const float* W_out = (const float*)d_in[7];
    const float* b_out = (const float*)d_in[8];
    float* out = (float*)d_out;

    const size_t need = (size_t)T_STEPS * GP * BATCH * sizeof(__half2); // 167.8 MB
    if (ws_size >= need) {
        __half2* gxbuf = (__half2*)d_ws;
        dim3 grid1(BATCH / 256, T_STEPS);   // 8192 blocks
        input_proj_s_kernel<<<grid1, 256, 0, stream>>>(word, W_ih, b_ih, b_hh, gxbuf);
        recurrence4h_kernel<<<BATCH / 64, 256, 0, stream>>>(
            gxbuf, W_hh, W_fc, b_fc, W_out, b_out, out);
    } else {
        lstm_word_fused_kernel<<<BATCH / 256, 256, 0, stream>>>(
            word, W_ih, W_hh, b_ih, b_hh, W_fc, b_fc, W_out, b_out, out);
    }
}

// Round 8
// 196.084 us; speedup vs baseline: 1.2422x; 1.0154x over previous
//
#include <hip/hip_runtime.h>
#include <hip/hip_fp16.h>

#define T_STEPS 32
#define BATCH   65536
#define IN_DIM  27
#define H_DIM   10
#define G_DIM   40          // 4*H
#define H2_DIM  5
#define GP      20          // packed gate-row pairs per (t, elem)

__device__ __forceinline__ float fast_exp2(float v) { return __builtin_amdgcn_exp2f(v); }
__device__ __forceinline__ float fast_rcp(float v)  { return __builtin_amdgcn_rcpf(v); }
__device__ __forceinline__ float fast_sigmoid(float v) {
    return fast_rcp(1.f + fast_exp2(v * -1.4426950408889634f));
}
__device__ __forceinline__ float fast_tanh(float v) {
    return 1.f - 2.f * fast_rcp(1.f + fast_exp2(v * 2.8853900817779268f));
}

// ---------------------------------------------------------------------------
// Pass 1 v4: scalar (SGPR) weights + E=2 elements/thread.
// SMEM s_loads return OOO -> compiler must lgkmcnt(0) per jp batch; that wait
// is per-WAVE, so computing 2 elements per thread amortizes it 2x. x1/x2 are
// pinned in VGPRs (asm "+v") to block the R6 LDS-remat failure mode.
// ---------------------------------------------------------------------------
__global__ __launch_bounds__(256, 4) void input_proj_s2_kernel(
    const float* __restrict__ word,   // [T, B, IN]
    const float* __restrict__ W_ih,   // [4H, IN] (contiguous 1080 floats)
    const float* __restrict__ b_ih,   // [4H]
    const float* __restrict__ b_hh,   // [4H]
    __half2* __restrict__ gx)         // [T, 20, B] packed row pairs
{
    __shared__ float s_x[256 * IN_DIM];   // 27648 B, reused for both chunks

    const int tid = threadIdx.x;
    const int t   = blockIdx.y;
    const int b0  = blockIdx.x * 512;     // block covers 512 elements

    // chunk A: elems [b0, b0+256)
    const float* srcA = word + ((size_t)t * BATCH + b0) * IN_DIM;
#pragma unroll
    for (int i = 0; i < IN_DIM; ++i) s_x[tid + 256 * i] = srcA[tid + 256 * i];
    __syncthreads();
    float x1[IN_DIM];
#pragma unroll
    for (int k = 0; k < IN_DIM; ++k) x1[k] = s_x[tid * IN_DIM + k];  // stride 27: conflict-free
#pragma unroll
    for (int k = 0; k < IN_DIM; ++k) asm volatile("" : "+v"(x1[k]));
    __syncthreads();

    // chunk B: elems [b0+256, b0+512)
    const float* srcB = srcA + 256 * IN_DIM;
#pragma unroll
    for (int i = 0; i < IN_DIM; ++i) s_x[tid + 256 * i] = srcB[tid + 256 * i];
    __syncthreads();
    float x2[IN_DIM];
#pragma unroll
    for (int k = 0; k < IN_DIM; ++k) x2[k] = s_x[tid * IN_DIM + k];
#pragma unroll
    for (int k = 0; k < IN_DIM; ++k) asm volatile("" : "+v"(x2[k]));

    __half2* dst1 = gx + (size_t)t * GP * BATCH + (size_t)(b0 + tid);
    __half2* dst2 = dst1 + 256;
#pragma unroll
    for (int jp = 0; jp < GP; ++jp) {
        const int r0 = 2 * jp, r1 = 2 * jp + 1;
        // wave-uniform weight/bias reads -> s_load; one lgkmcnt batch per jp
        // now feeds 108 FMAs (was 54)
        const float bb0 = b_ih[r0] + b_hh[r0];
        const float bb1 = b_ih[r1] + b_hh[r1];
        float a0 = bb0, a1 = bb1;     // elem A
        float c0 = bb0, c1 = bb1;     // elem B
        const float* w0 = W_ih + r0 * IN_DIM;
        const float* w1 = W_ih + r1 * IN_DIM;
#pragma unroll
        for (int k = 0; k < IN_DIM; ++k) {
            const float s0 = w0[k], s1 = w1[k];
            a0 = fmaf(s0, x1[k], a0);
            a1 = fmaf(s1, x1[k], a1);
            c0 = fmaf(s0, x2[k], c0);
            c1 = fmaf(s1, x2[k], c1);
        }
        dst1[(size_t)jp * BATCH] = __floats2half2_rn(a0, a1);   // coalesced 4B/lane
        dst2[(size_t)jp * BATCH] = __floats2half2_rn(c0, c1);
    }
}

// ---------------------------------------------------------------------------
// Pass 2 (R5-proven structure): 4 threads/elem, W_hh slice in VGPRs, fp16 gx.
// Change this round: prefetch depth 3 (~1200 cyc cover vs ~900 cyc HBM
// latency; depth 2's ~800 was marginal with only 2 resident waves/SIMD).
// ---------------------------------------------------------------------------
__global__
__attribute__((amdgpu_flat_work_group_size(256, 256), amdgpu_waves_per_eu(2, 2)))
void recurrence4h_kernel(
    const __half2* __restrict__ gx,   // [T, 20, B]
    const float* __restrict__ W_hh,   // [4H, H]
    const float* __restrict__ W_fc,   // [H2, H]
    const float* __restrict__ b_fc,   // [H2]
    const float* __restrict__ W_out,  // [1, H2]
    const float* __restrict__ b_out,  // [1]
    float* __restrict__ out)          // [B]
{
    const int tid = threadIdx.x;
    const int r   = tid & 3;                       // gate type: 0=i 1=f 2=g 3=o
    const int e   = blockIdx.x * 64 + (tid >> 2);  // batch element

    // my 10 W_hh rows -> registers
    float wh[10][10];
    {
        const float* wsrc = W_hh + (size_t)(r * 10) * H_DIM;
#pragma unroll
        for (int j = 0; j < 10; ++j)
#pragma unroll
            for (int n = 0; n < 10; ++n) wh[j][n] = wsrc[j * H_DIM + n];
    }

    const bool  is_tanh = (r == 2);
    const float kexp    = is_tanh ? 2.8853900817779268f : -1.4426950408889634f;
    const bool  m1 = (r & 1) != 0;
    const bool  m2 = (r & 2) != 0;

    float h[H_DIM], c[H_DIM];
#pragma unroll
    for (int m = 0; m < H_DIM; ++m) { h[m] = 0.f; c[m] = 0.f; }

    const __half2* gbase = gx + (size_t)(r * 5) * BATCH + e;
    const size_t tstride = (size_t)GP * BATCH;

    // prefetch pipeline depth 3: raw0=t, raw1=t+1, raw2=t+2 (kept packed)
    __half2 raw0[5], raw1[5], raw2[5];
#pragma unroll
    for (int p = 0; p < 5; ++p) raw0[p] = gbase[(size_t)p * BATCH];
#pragma unroll
    for (int p = 0; p < 5; ++p) raw1[p] = gbase[tstride + (size_t)p * BATCH];
#pragma unroll
    for (int p = 0; p < 5; ++p) raw2[p] = gbase[2 * tstride + (size_t)p * BATCH];

    for (int t = 0; t < T_STEPS; ++t) {
        // issue t+3 loads first
        __half2 raw3[5];
        {
            const int tn = (t + 3 < T_STEPS) ? (t + 3) : (T_STEPS - 1);
            const __half2* gp = gbase + (size_t)tn * tstride;
#pragma unroll
            for (int p = 0; p < 5; ++p) raw3[p] = gp[(size_t)p * BATCH];
        }

        // unpack current step (loaded 3 iterations ago -> no wait)
        float cur[10];
#pragma unroll
        for (int p = 0; p < 5; ++p) {
            cur[2 * p]     = __low2float(raw0[p]);
            cur[2 * p + 1] = __high2float(raw0[p]);
        }

        // h-part (VGPR weights) + my activation per owned row
        float act[10];
#pragma unroll
        for (int j = 0; j < 10; ++j) {
            float a = cur[j];
#pragma unroll
            for (int n = 0; n < H_DIM; ++n) a = fmaf(wh[j][n], h[n], a);
            const float e2 = fast_exp2(a * kexp);
            const float u  = fast_rcp(1.f + e2);
            act[j] = is_tanh ? fmaf(-2.f, u, 1.f) : u;
        }

        // quad all-gather + role decode + update (valid in ALL lanes)
#pragma unroll
        for (int m = 0; m < H_DIM; ++m) {
            const float s  = act[m];
            const float x1 = __shfl_xor(s, 1);
            const float x2 = __shfl_xor(s, 2);
            const float x3 = __shfl_xor(s, 3);
            const float tA  = m1 ? x1 : s;
            const float tB  = m1 ? x3 : x2;
            const float tAp = m1 ? s  : x1;
            const float tBp = m1 ? x2 : x3;
            const float iv = m2 ? tB  : tA;
            const float fv = m2 ? tBp : tAp;
            const float gv = m2 ? tA  : tB;
            const float ov = m2 ? tAp : tBp;
            const float cn = fmaf(fv, c[m], iv * gv);
            c[m] = fmaxf(cn, 0.f);               // relu(c) first...
            h[m] = ov * fast_tanh(c[m]);         // == relu(o*tanh(cn)), o>0
        }

        // rotate pipeline
#pragma unroll
        for (int p = 0; p < 5; ++p) { raw0[p] = raw1[p]; raw1[p] = raw2[p]; raw2[p] = raw3[p]; }
    }

    // head: one lane per quad
    if (r == 0) {
        float acc = b_out[0];
#pragma unroll
        for (int p = 0; p < H2_DIM; ++p) {
            float y = b_fc[p];
            const float* wf = W_fc + p * H_DIM;
#pragma unroll
            for (int m = 0; m < H_DIM; ++m) y = fmaf(wf[m], h[m], y);
            y = fmaxf(y, 0.f);
            acc = fmaf(W_out[p], y, acc);
        }
        out[e] = fast_sigmoid(acc);
    }
}

// ---------------------------------------------------------------------------
// Fallback (fused, known-correct) if workspace is too small.
// ---------------------------------------------------------------------------
__global__ __launch_bounds__(256, 1) void lstm_word_fused_kernel(
    const float* __restrict__ word, const float* __restrict__ W_ih,
    const float* __restrict__ W_hh, const float* __restrict__ b_ih,
    const float* __restrict__ b_hh, const float* __restrict__ W_fc,
    const float* __restrict__ b_fc, const float* __restrict__ W_out,
    const float* __restrict__ b_out, float* __restrict__ out)
{
    const int b = blockIdx.x * blockDim.x + threadIdx.x;
    float bias[G_DIM];
#pragma unroll
    for (int j = 0; j < G_DIM; ++j) bias[j] = b_ih[j] + b_hh[j];
    float h[H_DIM], c[H_DIM];
#pragma unroll
    for (int m = 0; m < H_DIM; ++m) { h[m] = 0.f; c[m] = 0.f; }
    const size_t t_stride = (size_t)BATCH * IN_DIM;
    const size_t row_off  = (size_t)b * IN_DIM;
    float x[IN_DIM];
    {
        const float* xp = word + row_off;
#pragma unroll
        for (int k = 0; k < IN_DIM; ++k) x[k] = xp[k];
    }
    for (int t = 0; t < T_STEPS; ++t) {
        float xn[IN_DIM];
        {
            const int tn = (t + 1 < T_STEPS) ? (t + 1) : t;
            const float* xq = word + (size_t)tn * t_stride + row_off;
#pragma unroll
            for (int k = 0; k < IN_DIM; ++k) xn[k] = xq[k];
        }
        float hn[H_DIM];
#pragma unroll
        for (int m = 0; m < H_DIM; ++m) {
            float ai = bias[m], af = bias[m + H_DIM], ag = bias[m + 2*H_DIM], ao = bias[m + 3*H_DIM];
            const float* wi = W_ih + m * IN_DIM;
            const float* wf = W_ih + (m + H_DIM) * IN_DIM;
            const float* wg = W_ih + (m + 2*H_DIM) * IN_DIM;
            const float* wo = W_ih + (m + 3*H_DIM) * IN_DIM;
#pragma unroll
            for (int k = 0; k < IN_DIM; ++k) {
                const float xv = x[k];
                ai = fmaf(wi[k], xv, ai); af = fmaf(wf[k], xv, af);
                ag = fmaf(wg[k], xv, ag); ao = fmaf(wo[k], xv, ao);
            }
            const float* hi = W_hh + m * H_DIM;
            const float* hf = W_hh + (m + H_DIM) * H_DIM;
            const float* hg = W_hh + (m + 2*H_DIM) * H_DIM;
            const float* ho = W_hh + (m + 3*H_DIM) * H_DIM;
#pragma unroll
            for (int n = 0; n < H_DIM; ++n) {
                const float hv = h[n];
                ai = fmaf(hi[n], hv, ai); af = fmaf(hf[n], hv, af);
                ag = fmaf(hg[n], hv, ag); ao = fmaf(ho[n], hv, ao);
            }
            const float iv = fast_sigmoid(ai), fv = fast_sigmoid(af);
            const float gv = fast_tanh(ag),    ov = fast_sigmoid(ao);
            const float cn = fmaf(fv, c[m], iv * gv);
            const float hv = ov * fast_tanh(cn);
            hn[m] = fmaxf(hv, 0.f);
            c[m]  = fmaxf(cn, 0.f);
        }
#pragma unroll
        for (int m = 0; m < H_DIM; ++m) h[m] = hn[m];
#pragma unroll
        for (int k = 0; k < IN_DIM; ++k) x[k] = xn[k];
    }
    float acc = b_out[0];
#pragma unroll
    for (int p = 0; p < H2_DIM; ++p) {
        float y = b_fc[p];
        const float* wf = W_fc + p * H_DIM;
#pragma unroll
        for (int m = 0; m < H_DIM; ++m) y = fmaf(wf[m], h[m], y);
        y = fmaxf(y, 0.f);
        acc = fmaf(W_out[p], y, acc);
    }
    out[b] = fast_sigmoid(acc);
}

extern "C" void kernel_launch(void* const* d_in, const int* in_sizes, int n_in,
                              void* d_out, int out_size, void* d_ws, size_t ws_size,
                              hipStream_t stream) {
    const float* word  = (const float*)d_in[0];
    const float* W_ih  = (const float*)d_in[1];
    const float* W_hh  = (const float*)d_in[2];
    const float* b_ih  = (const float*)d_in[3];
    const float* b_hh  = (const float*)d_in[4];
    const float* W_fc  = (const float*)d_in[5];
    const float* b_fc  = (const float*)d_in[6];
    const float* W_out = (const float*)d_in[7];
    const float* b_out = (const float*)d_in[8];
    float* out = (float*)d_out;

    const size_t need = (size_t)T_STEPS * GP * BATCH * sizeof(__half2); // 167.8 MB
    if (ws_size >= need) {
        __half2* gxbuf = (__half2*)d_ws;
        dim3 grid1(BATCH / 512, T_STEPS);   // 4096 blocks, E=2 per thread
        input_proj_s2_kernel<<<grid1, 256, 0, stream>>>(word, W_ih, b_ih, b_hh, gxbuf);
        recurrence4h_kernel<<<BATCH / 64, 256, 0, stream>>>(
            gxbuf, W_hh, W_fc, b_fc, W_out, b_out, out);
    } else {
        lstm_word_fused_kernel<<<BATCH / 256, 256, 0, stream>>>(
            word, W_ih, W_hh, b_ih, b_hh, W_fc, b_fc, W_out, b_out, out);
    }
}

// Round 9
// 191.656 us; speedup vs baseline: 1.2709x; 1.0231x over previous
//
#include <hip/hip_runtime.h>
#include <hip/hip_fp16.h>

#define T_STEPS 32
#define BATCH   65536
#define IN_DIM  27
#define H_DIM   10
#define G_DIM   40          // 4*H
#define H2_DIM  5
#define ROWS2M  (T_STEPS * BATCH)   // 2,097,152 flat rows (t*B + b)

typedef _Float16 f16_t;
typedef _Float16 f16x4 __attribute__((ext_vector_type(4)));
typedef float    f32x4 __attribute__((ext_vector_type(4)));

__device__ __forceinline__ float fast_exp2(float v) { return __builtin_amdgcn_exp2f(v); }
__device__ __forceinline__ float fast_rcp(float v)  { return __builtin_amdgcn_rcpf(v); }
__device__ __forceinline__ float fast_sigmoid(float v) {
    return fast_rcp(1.f + fast_exp2(v * -1.4426950408889634f));
}
__device__ __forceinline__ float fast_tanh(float v) {
    return 1.f - 2.f * fast_rcp(1.f + fast_exp2(v * 2.8853900817779268f));
}

// ---------------------------------------------------------------------------
// Pass 1 v5 (MFMA): gates = X[2M x 27] @ W_ih^T[27 x 40] + bias, as a real
// matrix-core GEMM. Weights live in B-fragments (12 VGPRs, loaded ONCE) --
// eliminating the per-jp s_load/ds_read lgkmcnt(0) serialization that held
// every previous pass-1 variant at ~1200 CU-cycles/element.
// Uses the legacy 16x16x16 f16 MFMA (documented CDNA layout:
//   A: row=lane&15, k=(lane>>4)*4+i;  B: col=lane&15, same k;
//   C/D: col=lane&15, row=(lane>>4)*4+reg  [m89-verified family])
// with K padded 27->32 via zeroed B (garbage A values multiply zero).
// Output gx[row][40] f16 row-major (row = t*B + b) -> pass-2 loads contiguous.
// ---------------------------------------------------------------------------
__global__ __launch_bounds__(256, 2) void input_proj_mfma(
    const float* __restrict__ word,   // [2M][27] flat (T,B,IN is contiguous)
    const float* __restrict__ W_ih,   // [40][27]
    const float* __restrict__ b_ih,   // [40]
    const float* __restrict__ b_hh,   // [40]
    f16_t* __restrict__ gx)           // [2M][40]
{
    __shared__ float s_pool[6928];    // 256 rows x 27 + 16 pad = 27712 B

    const int tid  = threadIdx.x;
    const int lane = tid & 63;
    const int w    = tid >> 6;        // wave id 0..3; wave owns rows [w*64, w*64+64)
    const int bn   = lane & 15;       // fragment M/N index
    const int kg   = lane >> 4;       // fragment k-group 0..3
    const size_t row0 = (size_t)blockIdx.x * 256;

    // ---- B-fragments (weights) + bias: loaded once, resident in VGPRs ----
    f16x4 bfrag[2][3];
    float bias[3];
#pragma unroll
    for (int nt = 0; nt < 3; ++nt) {
        const int g = nt * 16 + bn;            // gate row 0..47 (>=40 zeroed)
        const bool gok = (g < G_DIM);
        bias[nt] = gok ? (b_ih[g] + b_hh[g]) : 0.f;
#pragma unroll
        for (int ks = 0; ks < 2; ++ks) {
            f16x4 b;
#pragma unroll
            for (int i = 0; i < 4; ++i) {
                const int k = ks * 16 + kg * 4 + i;
                b[i] = (f16_t)((gok && k < IN_DIM) ? W_ih[g * IN_DIM + k] : 0.f);
            }
            bfrag[ks][nt] = b;
        }
    }

    // ---- stage 256 x-rows to LDS (coalesced flat copy) + zero the k-pad ----
    if (tid < 16) s_pool[6912 + tid] = 0.f;   // A-reads at k>=27 may land here
    const float* src = word + row0 * IN_DIM;
#pragma unroll
    for (int i = 0; i < IN_DIM; ++i) s_pool[tid + 256 * i] = src[tid + 256 * i];
    __syncthreads();

    // ---- A-fragments: 4 strips of 16 rows x 2 k-halves ----
    f16x4 afrag[4][2];
#pragma unroll
    for (int s = 0; s < 4; ++s) {
        const int r = w * 64 + s * 16 + bn;
        const float* xr = s_pool + r * IN_DIM;
#pragma unroll
        for (int ks = 0; ks < 2; ++ks) {
            const int k0 = ks * 16 + kg * 4;
            f16x4 a;
#pragma unroll
            for (int i = 0; i < 4; ++i) a[i] = (f16_t)xr[k0 + i];  // k>=27: finite garbage x B=0
            afrag[s][ks] = a;
        }
    }
    __syncthreads();   // all fragment reads done -> LDS reusable for epilogue

    // ---- MFMA: 4 strips x 3 n-tiles x 2 k-halves ----
    f32x4 acc[4][3];
#pragma unroll
    for (int s = 0; s < 4; ++s)
#pragma unroll
        for (int nt = 0; nt < 3; ++nt) {
            f32x4 c = {bias[nt], bias[nt], bias[nt], bias[nt]};
            c = __builtin_amdgcn_mfma_f32_16x16x16f16(afrag[s][0], bfrag[0][nt], c, 0, 0, 0);
            c = __builtin_amdgcn_mfma_f32_16x16x16f16(afrag[s][1], bfrag[1][nt], c, 0, 0, 0);
            acc[s][nt] = c;
        }

    // ---- epilogue: transpose C through LDS to row-major f16 [row][40] ----
    // LDS row stride 21 dwords (42 halfs): readback stride 21 coprime 32 -> conflict-free
    f16_t* hp = (f16_t*)s_pool;
#pragma unroll
    for (int s = 0; s < 4; ++s)
#pragma unroll
        for (int nt = 0; nt < 3; ++nt) {
            const int g = nt * 16 + bn;
            if (g < G_DIM) {
#pragma unroll
                for (int j = 0; j < 4; ++j) {
                    const int rr = w * 64 + s * 16 + kg * 4 + j;  // wave-private rows
                    hp[rr * 42 + g] = (f16_t)acc[s][nt][j];
                }
            }
        }
    // within-wave ds_write -> ds_read (same rows): compiler orders via lgkmcnt
    const int rr2 = w * 64 + lane;
    const unsigned* cr = (const unsigned*)s_pool + rr2 * 21;
    unsigned u[20];
#pragma unroll
    for (int c = 0; c < 20; ++c) u[c] = cr[c];
    unsigned* dst = (unsigned*)gx + (row0 + rr2) * 20;   // 80B/row, 16B-aligned
#pragma unroll
    for (int c = 0; c < 5; ++c) {
        uint4 q = {u[4 * c], u[4 * c + 1], u[4 * c + 2], u[4 * c + 3]};
        ((uint4*)dst)[c] = q;
    }
}

// ---------------------------------------------------------------------------
// Pass 2: 4 threads/elem, W_hh slice in VGPRs, depth-3 prefetch (R8 structure).
// gx layout now [row][40] f16: thread r reads 5 CONTIGUOUS dwords at
// row*80 + r*20 bytes (wave = 16 elems x 80B contiguous -> fully coalesced).
// ---------------------------------------------------------------------------
__global__
__attribute__((amdgpu_flat_work_group_size(256, 256), amdgpu_waves_per_eu(2, 2)))
void recurrence4h_kernel(
    const f16_t* __restrict__ gx,     // [2M][40]
    const float* __restrict__ W_hh,   // [4H, H]
    const float* __restrict__ W_fc,   // [H2, H]
    const float* __restrict__ b_fc,   // [H2]
    const float* __restrict__ W_out,  // [1, H2]
    const float* __restrict__ b_out,  // [1]
    float* __restrict__ out)          // [B]
{
    const int tid = threadIdx.x;
    const int r   = tid & 3;                       // gate type: 0=i 1=f 2=g 3=o
    const int e   = blockIdx.x * 64 + (tid >> 2);  // batch element

    float wh[10][10];
    {
        const float* wsrc = W_hh + (size_t)(r * 10) * H_DIM;
#pragma unroll
        for (int j = 0; j < 10; ++j)
#pragma unroll
            for (int n = 0; n < 10; ++n) wh[j][n] = wsrc[j * H_DIM + n];
    }

    const bool  is_tanh = (r == 2);
    const float kexp    = is_tanh ? 2.8853900817779268f : -1.4426950408889634f;
    const bool  m1 = (r & 1) != 0;
    const bool  m2 = (r & 2) != 0;

    float h[H_DIM], c[H_DIM];
#pragma unroll
    for (int m = 0; m < H_DIM; ++m) { h[m] = 0.f; c[m] = 0.f; }

    // my 5 dwords per step: base + t*(B*20) + e*20 + r*5
    const unsigned* gb = (const unsigned*)gx + (size_t)e * 20 + r * 5;
    const size_t tstride = (size_t)BATCH * 20;

    unsigned raw0[5], raw1[5], raw2[5];
#pragma unroll
    for (int p = 0; p < 5; ++p) raw0[p] = gb[p];
#pragma unroll
    for (int p = 0; p < 5; ++p) raw1[p] = gb[tstride + p];
#pragma unroll
    for (int p = 0; p < 5; ++p) raw2[p] = gb[2 * tstride + p];

    for (int t = 0; t < T_STEPS; ++t) {
        unsigned raw3[5];
        {
            const int tn = (t + 3 < T_STEPS) ? (t + 3) : (T_STEPS - 1);
            const unsigned* gp = gb + (size_t)tn * tstride;
#pragma unroll
            for (int p = 0; p < 5; ++p) raw3[p] = gp[p];
        }

        float cur[10];
#pragma unroll
        for (int p = 0; p < 5; ++p) {
            const __half2 h2 = *(const __half2*)&raw0[p];
            cur[2 * p]     = __low2float(h2);
            cur[2 * p + 1] = __high2float(h2);
        }

        float act[10];
#pragma unroll
        for (int j = 0; j < 10; ++j) {
            float a = cur[j];
#pragma unroll
            for (int n = 0; n < H_DIM; ++n) a = fmaf(wh[j][n], h[n], a);
            const float e2 = fast_exp2(a * kexp);
            const float u  = fast_rcp(1.f + e2);
            act[j] = is_tanh ? fmaf(-2.f, u, 1.f) : u;
        }

#pragma unroll
        for (int m = 0; m < H_DIM; ++m) {
            const float s  = act[m];
            const float x1 = __shfl_xor(s, 1);
            const float x2 = __shfl_xor(s, 2);
            const float x3 = __shfl_xor(s, 3);
            const float tA  = m1 ? x1 : s;
            const float tB  = m1 ? x3 : x2;
            const float tAp = m1 ? s  : x1;
            const float tBp = m1 ? x2 : x3;
            const float iv = m2 ? tB  : tA;
            const float fv = m2 ? tBp : tAp;
            const float gv = m2 ? tA  : tB;
            const float ov = m2 ? tAp : tBp;
            const float cn = fmaf(fv, c[m], iv * gv);
            c[m] = fmaxf(cn, 0.f);
            h[m] = ov * fast_tanh(c[m]);         // == relu(o*tanh(cn)), o>0
        }

#pragma unroll
        for (int p = 0; p < 5; ++p) { raw0[p] = raw1[p]; raw1[p] = raw2[p]; raw2[p] = raw3[p]; }
    }

    if (r == 0) {
        float acc = b_out[0];
#pragma unroll
        for (int p = 0; p < H2_DIM; ++p) {
            float y = b_fc[p];
            const float* wf = W_fc + p * H_DIM;
#pragma unroll
            for (int m = 0; m < H_DIM; ++m) y = fmaf(wf[m], h[m], y);
            y = fmaxf(y, 0.f);
            acc = fmaf(W_out[p], y, acc);
        }
        out[e] = fast_sigmoid(acc);
    }
}

// ---------------------------------------------------------------------------
// Fallback (fused, known-correct) if workspace is too small.
// ---------------------------------------------------------------------------
__global__ __launch_bounds__(256, 1) void lstm_word_fused_kernel(
    const float* __restrict__ word, const float* __restrict__ W_ih,
    const float* __restrict__ W_hh, const float* __restrict__ b_ih,
    const float* __restrict__ b_hh, const float* __restrict__ W_fc,
    const float* __restrict__ b_fc, const float* __restrict__ W_out,
    const float* __restrict__ b_out, float* __restrict__ out)
{
    const int b = blockIdx.x * blockDim.x + threadIdx.x;
    float bias[G_DIM];
#pragma unroll
    for (int j = 0; j < G_DIM; ++j) bias[j] = b_ih[j] + b_hh[j];
    float h[H_DIM], c[H_DIM];
#pragma unroll
    for (int m = 0; m < H_DIM; ++m) { h[m] = 0.f; c[m] = 0.f; }
    const size_t t_stride = (size_t)BATCH * IN_DIM;
    const size_t row_off  = (size_t)b * IN_DIM;
    float x[IN_DIM];
    {
        const float* xp = word + row_off;
#pragma unroll
        for (int k = 0; k < IN_DIM; ++k) x[k] = xp[k];
    }
    for (int t = 0; t < T_STEPS; ++t) {
        float xn[IN_DIM];
        {
            const int tn = (t + 1 < T_STEPS) ? (t + 1) : t;
            const float* xq = word + (size_t)tn * t_stride + row_off;
#pragma unroll
            for (int k = 0; k < IN_DIM; ++k) xn[k] = xq[k];
        }
        float hn[H_DIM];
#pragma unroll
        for (int m = 0; m < H_DIM; ++m) {
            float ai = bias[m], af = bias[m + H_DIM], ag = bias[m + 2*H_DIM], ao = bias[m + 3*H_DIM];
            const float* wi = W_ih + m * IN_DIM;
            const float* wf = W_ih + (m + H_DIM) * IN_DIM;
            const float* wg = W_ih + (m + 2*H_DIM) * IN_DIM;
            const float* wo = W_ih + (m + 3*H_DIM) * IN_DIM;
#pragma unroll
            for (int k = 0; k < IN_DIM; ++k) {
                const float xv = x[k];
                ai = fmaf(wi[k], xv, ai); af = fmaf(wf[k], xv, af);
                ag = fmaf(wg[k], xv, ag); ao = fmaf(wo[k], xv, ao);
            }
            const float* hi = W_hh + m * H_DIM;
            const float* hf = W_hh + (m + H_DIM) * H_DIM;
            const float* hg = W_hh + (m + 2*H_DIM) * H_DIM;
            const float* ho = W_hh + (m + 3*H_DIM) * H_DIM;
#pragma unroll
            for (int n = 0; n < H_DIM; ++n) {
                const float hv = h[n];
                ai = fmaf(hi[n], hv, ai); af = fmaf(hf[n], hv, af);
                ag = fmaf(hg[n], hv, ag); ao = fmaf(ho[n], hv, ao);
            }
            const float iv = fast_sigmoid(ai), fv = fast_sigmoid(af);
            const float gv = fast_tanh(ag),    ov = fast_sigmoid(ao);
            const float cn = fmaf(fv, c[m], iv * gv);
            const float hv = ov * fast_tanh(cn);
            hn[m] = fmaxf(hv, 0.f);
            c[m]  = fmaxf(cn, 0.f);
        }
#pragma unroll
        for (int m = 0; m < H_DIM; ++m) h[m] = hn[m];
#pragma unroll
        for (int k = 0; k < IN_DIM; ++k) x[k] = xn[k];
    }
    float acc = b_out[0];
#pragma unroll
    for (int p = 0; p < H2_DIM; ++p) {
        float y = b_fc[p];
        const float* wf = W_fc + p * H_DIM;
#pragma unroll
        for (int m = 0; m < H_DIM; ++m) y = fmaf(wf[m], h[m], y);
        y = fmaxf(y, 0.f);
        acc = fmaf(W_out[p], y, acc);
    }
    out[b] = fast_sigmoid(acc);
}

extern "C" void kernel_launch(void* const* d_in, const int* in_sizes, int n_in,
                              void* d_out, int out_size, void* d_ws, size_t ws_size,
                              hipStream_t stream) {
    const float* word  = (const float*)d_in[0];
    const float* W_ih  = (const float*)d_in[1];
    const float* W_hh  = (const float*)d_in[2];
    const float* b_ih  = (const float*)d_in[3];
    const float* b_hh  = (const float*)d_in[4];
    const float* W_fc  = (const float*)d_in[5];
    const float* b_fc  = (const float*)d_in[6];
    const float* W_out = (const float*)d_in[7];
    const float* b_out = (const float*)d_in[8];
    float* out = (float*)d_out;

    const size_t need = (size_t)ROWS2M * G_DIM * sizeof(f16_t); // 167.8 MB
    if (ws_size >= need) {
        f16_t* gxbuf = (f16_t*)d_ws;
        input_proj_mfma<<<ROWS2M / 256, 256, 0, stream>>>(word, W_ih, b_ih, b_hh, gxbuf);
        recurrence4h_kernel<<<BATCH / 64, 256, 0, stream>>>(
            gxbuf, W_hh, W_fc, b_fc, W_out, b_out, out);
    } else {
        lstm_word_fused_kernel<<<BATCH / 256, 256, 0, stream>>>(
            word, W_ih, W_hh, b_ih, b_hh, W_fc, b_fc, W_out, b_out, out);
    }
}

// Round 10
// 54.809 us; speedup vs baseline: 4.4442x; 3.4968x over previous
//
#include <hip/hip_runtime.h>

#define T_STEPS 32
#define BATCH   65536
#define IN_DIM  27
#define H_DIM   10
#define H2_DIM  5

typedef _Float16 f16_t;
typedef _Float16 f16x4 __attribute__((ext_vector_type(4)));
typedef float    f32x4 __attribute__((ext_vector_type(4)));

__device__ __forceinline__ float fast_exp2(float v) { return __builtin_amdgcn_exp2f(v); }
__device__ __forceinline__ float fast_rcp(float v)  { return __builtin_amdgcn_rcpf(v); }
__device__ __forceinline__ float fast_sigmoid(float v) {
    return fast_rcp(1.f + fast_exp2(v * -1.4426950408889634f));
}
__device__ __forceinline__ float fast_tanh(float v) {
    return 1.f - 2.f * fast_rcp(1.f + fast_exp2(v * 2.8853900817779268f));
}

// unaligned-safe 16B global load (word rows are 108 B -> only 4B alignment)
__device__ __forceinline__ f32x4 load4u(const float* p) {
    f32x4 v; __builtin_memcpy(&v, p, 16); return v;
}

// ---------------------------------------------------------------------------
// Fully-fused MFMA LSTM. One wave = 16 batch elements x all 32 steps.
// gx is never materialized (R5-R9 showed both passes pinned at the gx
// 336 MB round-trip). Gate dim padded 40->64 (4 n-tiles = one per gate TYPE,
// rows type*10+unit, cols 10..15 zero): C layout (validated by R9 pass:
// lane(kg,bn) slot acc[nt][reg] = (elem kg*4+reg, col bn)) then gives each
// lane ALL FOUR gate types of (elem, unit bn) -> update needs no shuffles.
// h feedback: per-wave LDS table (C-layout write, A-fragment read).
// x K-split: ks0 = cols 0..15; ks1 = cols 11..26 with B rows j<5 zeroed
// (overlap masked, and loads never cross the 27-float row end -> no OOB).
// ---------------------------------------------------------------------------
__global__
__attribute__((amdgpu_flat_work_group_size(256, 256), amdgpu_waves_per_eu(4, 4)))
void lstm_fused_mfma(
    const float* __restrict__ word,   // [T, B, IN]
    const float* __restrict__ W_ih,   // [40, 27]
    const float* __restrict__ W_hh,   // [40, 10]
    const float* __restrict__ b_ih,   // [40]
    const float* __restrict__ b_hh,   // [40]
    const float* __restrict__ W_fc,   // [5, 10]
    const float* __restrict__ b_fc,   // [5]
    const float* __restrict__ W_out,  // [1, 5]
    const float* __restrict__ b_out,  // [1]
    float* __restrict__ out)          // [B]
{
    // per-wave h table: 16 elems x 20 halfs (units 0..15 used; stride 20 ->
    // b64 reads 8B-aligned, dword idx bn*10+2kg: 16 distinct banks, conflict-free)
    __shared__ __align__(16) f16_t s_h[4][16 * 20];   // 2560 B total

    const int tid  = threadIdx.x;
    const int lane = tid & 63;
    const int w    = tid >> 6;
    const int bn   = lane & 15;       // fragment col (gate unit) / A row (elem)
    const int kg   = lane >> 4;       // fragment k-group
    const int e0   = blockIdx.x * 64 + w * 16;   // wave's 16 elements

    // ---- resident weight fragments (loaded once; gates padded 40->64) ----
    const bool gok = (bn < H_DIM);    // col bn is a real unit?
    f16x4 bfx0[4], bfx1[4], bfh[4];
    float bias[4];
#pragma unroll
    for (int nt = 0; nt < 4; ++nt) {  // nt = gate type: 0=i 1=f 2=g 3=o
        const int g = nt * H_DIM + bn;            // real gate row
        bias[nt] = gok ? (b_ih[g] + b_hh[g]) : 0.f;
#pragma unroll
        for (int i = 0; i < 4; ++i) {
            const int k = kg * 4 + i;             // logical k 0..15
            bfx0[nt][i] = (f16_t)(gok ? W_ih[g * IN_DIM + k] : 0.f);          // cols 0..15
            bfx1[nt][i] = (f16_t)((gok && k >= 5) ? W_ih[g * IN_DIM + 11 + k] : 0.f); // cols 16..26
            bfh[nt][i]  = (f16_t)((gok && k < H_DIM) ? W_hh[g * H_DIM + k] : 0.f);    // units 0..9
        }
    }

    f16_t* tb = &s_h[w][0];
    // zero exactly the slots the A_h reads touch (h0 = 0)
    {
        f16x4 z = {(f16_t)0.f, (f16_t)0.f, (f16_t)0.f, (f16_t)0.f};
        *(f16x4*)(tb + bn * 20 + kg * 4) = z;
    }

    float c[4];
#pragma unroll
    for (int r = 0; r < 4; ++r) c[r] = 0.f;

    // x addressing: A row = elem bn; ks0 at col kg*4, ks1 at col 11+kg*4 (max 26)
    const float* xbase = word + (size_t)(e0 + bn) * IN_DIM;
    const size_t tstep = (size_t)BATCH * IN_DIM;
    const int c0 = kg * 4, c1 = 11 + kg * 4;

    f32x4 xa = load4u(xbase + c0);
    f32x4 xb = load4u(xbase + c1);

    for (int t = 0; t < T_STEPS; ++t) {
        // ---- prefetch next step's x (clamped re-read on last iter: L1-hot) ----
        const float* xr = xbase + (size_t)((t + 1 < T_STEPS) ? t + 1 : t) * tstep;
        f32x4 na = load4u(xr + c0);
        f32x4 nb = load4u(xr + c1);

        // ---- previous h as A-fragment: A[row=bn=elem][k=kg*4+i=unit] ----
        const f16x4 ah = *(const f16x4*)(tb + bn * 20 + kg * 4);

        // ---- current x -> f16 A-fragments ----
        f16x4 ax0, ax1;
#pragma unroll
        for (int i = 0; i < 4; ++i) { ax0[i] = (f16_t)xa[i]; ax1[i] = (f16_t)xb[i]; }

        // ---- gates = bias + X@Wih^T + H@Whh^T  (12 MFMA, weights resident) ----
        f32x4 acc[4];
#pragma unroll
        for (int nt = 0; nt < 4; ++nt) {
            f32x4 a = {bias[nt], bias[nt], bias[nt], bias[nt]};
            a = __builtin_amdgcn_mfma_f32_16x16x16f16(ax0, bfx0[nt], a, 0, 0, 0);
            a = __builtin_amdgcn_mfma_f32_16x16x16f16(ax1, bfx1[nt], a, 0, 0, 0);
            a = __builtin_amdgcn_mfma_f32_16x16x16f16(ah,  bfh[nt],  a, 0, 0, 0);
            acc[nt] = a;
        }

        // ---- update: lane owns (elem kg*4+reg, unit bn); all 4 types local ----
#pragma unroll
        for (int reg = 0; reg < 4; ++reg) {
            const float iv = fast_sigmoid(acc[0][reg]);
            const float fv = fast_sigmoid(acc[1][reg]);
            const float gv = fast_tanh   (acc[2][reg]);
            const float ov = fast_sigmoid(acc[3][reg]);
            const float cn = fmaf(fv, c[reg], iv * gv);
            c[reg] = fmaxf(cn, 0.f);                  // relu'd carry
            const float hv = ov * fast_tanh(c[reg]);  // >=0: relu(h) == h
            tb[(kg * 4 + reg) * 20 + bn] = (f16_t)hv; // C-layout -> table
        }

        xa = na; xb = nb;
    }

    // ---- head on lanes 0..15 (one per elem): FC(10->5) relu -> 5->1 -> sigmoid ----
    if (lane < 16) {
        float hv[H_DIM];
#pragma unroll
        for (int u = 0; u < H_DIM; ++u) hv[u] = (float)tb[lane * 20 + u];
        float accv = b_out[0];
#pragma unroll
        for (int p = 0; p < H2_DIM; ++p) {
            float y = b_fc[p];
#pragma unroll
            for (int m = 0; m < H_DIM; ++m) y = fmaf(W_fc[p * H_DIM + m], hv[m], y);
            y = fmaxf(y, 0.f);
            accv = fmaf(W_out[p], y, accv);
        }
        out[e0 + lane] = fast_sigmoid(accv);
    }
}

extern "C" void kernel_launch(void* const* d_in, const int* in_sizes, int n_in,
                              void* d_out, int out_size, void* d_ws, size_t ws_size,
                              hipStream_t stream) {
    const float* word  = (const float*)d_in[0];
    const float* W_ih  = (const float*)d_in[1];
    const float* W_hh  = (const float*)d_in[2];
    const float* b_ih  = (const float*)d_in[3];
    const float* b_hh  = (const float*)d_in[4];
    const float* W_fc  = (const float*)d_in[5];
    const float* b_fc  = (const float*)d_in[6];
    const float* W_out = (const float*)d_in[7];
    const float* b_out = (const float*)d_in[8];
    float* out = (float*)d_out;

    // 16 elems/wave, 4 waves/block -> 64 elems/block -> 1024 blocks (4/CU)
    lstm_fused_mfma<<<BATCH / 64, 256, 0, stream>>>(
        word, W_ih, W_hh, b_ih, b_hh, W_fc, b_fc, W_out, b_out, out);
}